// Round 7
// baseline (564.512 us; speedup 1.0000x reference)
//
#include <hip/hip_runtime.h>

// DirectionalFilterBank: 3-level binary tree of (shear ±1 -> depthwise 9x9 conv).
// shear(x,s)[h,w] = 0.5*(x[h,c0]+x[h,c0+1]), c0 = w + s*h + (s>0 ? -128 : 127),
// w in [0,256); conv zero-pads the SHEARED image by 4. Filter rank-2 separable:
// filt_c = -(A (x) A) + (B (x) B) [+ center delta, c==0].
//
// Model R0-R6: instruction lever exhausted (R6: -8% instr -> -2% time). Per-conv
// L2/L3 traffic 134MB / 35us = 3.8 TB/s combined -> suspected bandwidth floor.
// THIS ROUND: each block computes BOTH parities of one parent tile sequentially.
// The two parities read the SAME parent rows (h0-4..h0+35; only col windows
// differ), so phase-1 staging re-reads ~40KB that phase-0 just pulled -> L2-hot.
// Parent fetched from L3/HBM once per block instead of twice: total L3 traffic
// 1.85 -> 1.39 GB (-25%). 14 -> 7 launches. Geometry/LDS/occupancy unchanged.
// R4's different-block pairing was neutral because both blocks' reads still hit
// L3; same-block sequential pairing is what converts the 2nd read to L2.
//
// Scratch liveness (MiB regions in out, verified launch-by-launch):
//   A=[0,66) AA=[128,194) AB=[322,388) B=[256,322) BA=[384,450); BB unpadded->ws.
//   L1(x->A,B) L2(A->AA,AB) L3(AA->o0,o1) L4(AB->o2,o3) L5(B->BA,BB)
//   L6(BA->o4,o5) L7(BB->o6,o7). No launch reads what it writes; no final
//   overwritten after write; padded extent 65.01MiB < 66MiB spacing.

#define B_ 4
#define C_ 64
#define H_ 256
#define W_ 256
#define TH 32                 // output rows per block
#define SROWS (TH + 8)        // 40 staged sheared rows
#define SCOLS (W_ + 8)        // 264 staged cols; LDS = 41.25 KiB
#define NPB 2048              // blocks per launch = 4*64*8 (each does 2 convs)
#define PSTRIDE 260           // padded row stride (floats); right-pad==next left-pad
#define PPLANE (H_ * PSTRIDE)

// 4-byte-aligned float4 view (shear loads are dword- but not 16B-aligned).
struct alignas(4) f4u { float x, y, z, w; };

template<bool SRC_PAD, bool DST_PAD>
static __device__ __forceinline__ void conv_phase(
    const float* __restrict__ in, float* __restrict__ dst,
    const float* __restrict__ filt, const int parity,
    float (&s_sh)[SROWS][SCOLS])
{
    const int tid  = threadIdx.x;
    const int bid  = (int)blockIdx.x;
    const int tile = bid & 7;            // H/TH = 8
    const int c    = (bid >> 3) & 63;    // C = 64
    const int b    = bid >> 9;
    const int h0   = tile * TH;
    const int sign = parity ? -1 : 1;
    const int off  = parity ? 127 : -128;

    const int plane_idx = b * C_ + c;
    const float* base = in + (size_t)plane_idx * (size_t)(SRC_PAD ? PPLANE : H_ * W_);

    // ---- stage sheared rows h0-4 .. h0+35 (wave w: rows w+4u, lane: 4 cols) ----
    {
        const int wave = tid >> 6;
        const int lane = tid & 63;

        // LDS halo cols [0,4) and [260,264) are always zero
        if (tid < 80) {
            const int r = tid >> 1;
            *(float4*)&s_sh[r][(tid & 1) ? 260 : 0] = make_float4(0.f, 0.f, 0.f, 0.f);
        }

        #pragma unroll
        for (int u = 0; u < 10; ++u) {
            const int r  = wave + u * 4;
            const int hr = h0 + r - 4;
            float4 v = make_float4(0.f, 0.f, 0.f, 0.f);
            if ((unsigned)hr < 256u) {                   // wave-coherent
                if (SRC_PAD) {
                    // padded source: value(hr,w) = row[w+4], legal for w in [-4,259]
                    const float* row = base + (size_t)hr * PSTRIDE;
                    const int d  = off + sign * hr + 4 + lane * 4;  // c0+4
                    const int dc = min(max(d, 0), 259);
                    const bool valid = (unsigned)d < 260u;          // c0 in [-4,255]
                    const f4u  a = *(const f4u*)(row + dc);
                    const float e = row[dc + 4];                    // <= row+263, legal
                    v.x = valid ? 0.5f * (a.x + a.y) : 0.f;
                    v.y = valid ? 0.5f * (a.y + a.z) : 0.f;
                    v.z = valid ? 0.5f * (a.z + a.w) : 0.f;
                    v.w = valid ? 0.5f * (a.w + e)   : 0.f;
                } else {
                    // unpadded source: branchless clamp + per-element zero masks
                    const float* row = base + (size_t)hr * W_;
                    const int c0 = off + sign * hr + lane * 4;
                    const int i0 = min(max(c0,     0), 255);
                    const int i1 = min(max(c0 + 1, 0), 255);
                    const int i2 = min(max(c0 + 2, 0), 255);
                    const int i3 = min(max(c0 + 3, 0), 255);
                    const int i4 = min(max(c0 + 4, 0), 255);
                    float t0 = row[i0];
                    float t1 = row[i1];
                    float t2 = row[i2];
                    float t3 = row[i3];
                    float t4 = row[i4];
                    t0 = ((unsigned)c0       < 256u) ? t0 : 0.f;
                    t1 = ((unsigned)(c0 + 1) < 256u) ? t1 : 0.f;
                    t2 = ((unsigned)(c0 + 2) < 256u) ? t2 : 0.f;
                    t3 = ((unsigned)(c0 + 3) < 256u) ? t3 : 0.f;
                    t4 = ((unsigned)(c0 + 4) < 256u) ? t4 : 0.f;
                    v.x = 0.5f * (t0 + t1);
                    v.y = 0.5f * (t1 + t2);
                    v.z = 0.5f * (t2 + t3);
                    v.w = 0.5f * (t3 + t4);
                }
            }
            *(float4*)&s_sh[r][4 + lane * 4] = v;        // 16B-aligned
        }
    }

    // ---- separable factors from channel 1 (uniform; identical for all c) ----
    const float* f1 = filt + 81;
    const float A4  = sqrtf(fmaxf(-f1[4 * 9 + 4], 0.f));
    const float rA4 = 1.f / A4;
    const float A0  = -f1[0 * 9 + 4] * rA4;
    const float A2  = -f1[2 * 9 + 4] * rA4;
    const float A6  = -f1[6 * 9 + 4] * rA4;
    const float A8  = -f1[8 * 9 + 4] * rA4;
    const float B5  = sqrtf(fmaxf(f1[5 * 9 + 5], 0.f));
    const float rB5 = 1.f / B5;
    const float B1  = f1[1 * 9 + 5] * rB5;
    const float B3  = f1[3 * 9 + 5] * rB5;
    const float B7  = f1[7 * 9 + 5] * rB5;
    const float vc[9] = {-A0, B1, -A2, B3, -A4, B5, -A6, B7, -A8};

    __syncthreads();

    // ---- compute: 4 row-groups x 8 rows; thread = 4 cols x 8 rows (window 16) ----
    const int rg   = tid >> 6;           // 0..3 -> out rows rg*8 .. rg*8+7
    const int lane = tid & 63;
    const int w0   = lane * 4;

    float acc[8][4];
    #pragma unroll
    for (int i = 0; i < 8; ++i)
        #pragma unroll
        for (int j = 0; j < 4; ++j) acc[i][j] = 0.f;

    __builtin_amdgcn_s_setprio(1);
    #pragma unroll
    for (int t = 0; t < 16; ++t) {       // staged rows rg*8 + t
        const int rr = rg * 8 + t;
        const float4 sa = *(const float4*)&s_sh[rr][w0];
        const float4 sb = *(const float4*)&s_sh[rr][w0 + 4];
        const float4 sc4 = *(const float4*)&s_sh[rr][w0 + 8];
        const float s[12] = {sa.x, sa.y, sa.z, sa.w,
                             sb.x, sb.y, sb.z, sb.w,
                             sc4.x, sc4.y, sc4.z, sc4.w};
        float ha[4], hb[4];
        #pragma unroll
        for (int j = 0; j < 4; ++j) {
            ha[j] = fmaf(A8, s[j + 8],
                    fmaf(A6, s[j + 6],
                    fmaf(A4, s[j + 4],
                    fmaf(A2, s[j + 2], A0 * s[j]))));
            hb[j] = fmaf(B7, s[j + 7],
                    fmaf(B5, s[j + 5],
                    fmaf(B3, s[j + 3], B1 * s[j + 1])));
        }
        #pragma unroll
        for (int i = 0; i < 8; ++i) {
            const int ky = t - i;        // compile-time after unroll
            if (ky >= 0 && ky < 9) {
                #pragma unroll
                for (int j = 0; j < 4; ++j) {
                    const float hv = (ky & 1) ? hb[j] : ha[j];
                    acc[i][j] = fmaf(vc[ky], hv, acc[i][j]);
                }
            }
        }
    }
    __builtin_amdgcn_s_setprio(0);

    // channel-0 delta: += sheared image value at the output location
    if (c == 0) {
        #pragma unroll
        for (int i = 0; i < 8; ++i) {
            const float4 sv = *(const float4*)&s_sh[rg * 8 + i + 4][w0 + 4];
            acc[i][0] += sv.x; acc[i][1] += sv.y; acc[i][2] += sv.z; acc[i][3] += sv.w;
        }
    }

    if (DST_PAD) {
        float* plane = dst + (size_t)plane_idx * PPLANE;
        // halo: zero right-pad of each owned row == left-pad of next row
        if (lane < 8)
            *(float4*)(plane + (size_t)(h0 + rg * 8 + lane + 1) * PSTRIDE) =
                make_float4(0.f, 0.f, 0.f, 0.f);
        if (bid == 0 && tid == 8)        // very first plane's row-0 left pad
            *(float4*)dst = make_float4(0.f, 0.f, 0.f, 0.f);
        float* optr = plane + (size_t)(h0 + rg * 8) * PSTRIDE + 4 + w0;
        #pragma unroll
        for (int i = 0; i < 8; ++i) {
            const float4 v = {acc[i][0], acc[i][1], acc[i][2], acc[i][3]};
            *(float4*)(optr + (size_t)i * PSTRIDE) = v;  // 16B-aligned (1040%16==0)
        }
    } else {
        float* optr = dst + (((size_t)plane_idx) * H_ + h0 + rg * 8) * (size_t)W_ + w0;
        #pragma unroll
        for (int i = 0; i < 8; ++i) {
            const float4 v = {acc[i][0], acc[i][1], acc[i][2], acc[i][3]};
            *(float4*)(optr + (size_t)i * W_) = v;
        }
    }
}

// One block = one parent tile -> both parity children, staged sequentially.
// Phase 1 re-reads the same parent rows as phase 0 (only col windows differ)
// -> second read is L2-hit; parent pulled from L3/HBM once.
template<bool SP, bool DP0, bool DP1>
__global__ __launch_bounds__(256) void shear_sepconv_pair(
    const float* __restrict__ in, float* __restrict__ dst0,
    float* __restrict__ dst1, const float* __restrict__ filt)
{
    __shared__ float s_sh[SROWS][SCOLS];
    conv_phase<SP, DP0>(in, dst0, filt, 0, s_sh);
    __syncthreads();   // all s_sh reads of phase 0 done before restaging
    conv_phase<SP, DP1>(in, dst1, filt, 1, s_sh);
}

extern "C" void kernel_launch(void* const* d_in, const int* in_sizes, int n_in,
                              void* d_out, int out_size, void* d_ws, size_t ws_size,
                              hipStream_t stream) {
    const float* x    = (const float*)d_in[0];
    const float* filt = (const float*)d_in[1];
    float* out = (float*)d_out;
    float* wsb = (float*)d_ws;          // 64 MiB spare: BB (unpadded) lives here
    const size_t N = (size_t)B_ * C_ * H_ * W_;   // floats per 64MiB slot

    float* S[8];
    for (int k = 0; k < 8; ++k) S[k] = out + (size_t)k * N;

    auto MBo = [&](int mb) { return out + (((size_t)mb) << 20) / 4; };
    float* A_  = MBo(0);     // [  0, 66) MiB, dies L2
    float* AA_ = MBo(128);   // [128,194), dies L3 (out2,3 written later at L4)
    float* AB_ = MBo(322);   // [322,388), dies L4
    float* Bb  = MBo(256);   // [256,322), dies L5 (out4,5 written later at L6)
    float* BA_ = MBo(384);   // [384,450), dies L6 (out6,7 written later at L7)
    float* BB_ = wsb;        // unpadded, 64 MiB

    const dim3 grid(NPB);
    const dim3 block(256);

    #define L(SP, DP0, DP1, src, d0, d1) \
        shear_sepconv_pair<SP, DP0, DP1><<<grid, block, 0, stream>>>(src, d0, d1, filt)

    L(false, true , true , x,   A_,   Bb );   // L1: A (p0), B (p1)
    L(true , true , true , A_,  AA_,  AB_);   // L2: AA, AB
    L(true , false, false, AA_, S[0], S[1]);  // L3: out0, out1
    L(true , false, false, AB_, S[2], S[3]);  // L4: out2, out3
    L(true , true , false, Bb,  BA_,  BB_);   // L5: BA (padded), BB (unpadded->ws)
    L(true , false, false, BA_, S[4], S[5]);  // L6: out4, out5
    L(false, false, false, BB_, S[6], S[7]);  // L7: out6, out7
    #undef L
}